// Round 1
// 313.323 us; speedup vs baseline: 1.0009x; 1.0009x over previous
//
#include <hip/hip_runtime.h>

// image2patch: out[b, i*126+j, r*6+c] = x[b, 0, 2*i + r, 2*j + c]
// IMAGE_SIZE=256, PSIZE=6, STRIDE=2, NPOS=126, BATCH=128, fp32.
//
// R1: coalesced stores + divergent global loads = TA/TD serialization -> LDS staging.
// R2 (this round): the ~130us kernel (184us of dur_us is harness re-poison fill) is
// issue-bound, not BW-bound:
//   a) emit loop re-derived j/k/r/c per float4 (~40 VALU) -> stride-252 loop makes
//      per-thread (k0,r,c) and LDS addrs loop-invariant (body = 4 ds_read + 4 add + store)
//   b) LDSW=257 gave up-to-6-way emit-read bank conflicts; LDSW=267 (bank=11r+2j+c)
//      caps at 3-way (enumerated over the 9 (r,c) classes x 7 j-group shifts)
//   c) staging scalar writes at 4*col4+e were stride-4-dword = 8-way conflict;
//      row=idx%6 interleave injects 11*row into the bank index (~2-way)
//   d) XCD-chunked swizzle (16128 = 8*2016 exact): each XCD owns whole batches ->
//      image rows reused 3x in its L2, FETCH ~97MB -> ~35MB

#define IMG 256
#define PSZ 6
#define NPOS 126
#define BATCHN 128
#define LDSW 267                 // 267 mod 32 = 11: mixed-parity bank spread, max 3-way
#define NV 1134                  // 126 patches * 36 floats / 4 = float4s per band
#define NXCD 8

__global__ __launch_bounds__(256) void image2patch_kernel(
    const float* __restrict__ x, float* __restrict__ out) {
  __shared__ float tile[PSZ * LDSW];

  // ---- XCD-chunked bijective swizzle (grid = 16128 = 8 * 2016) ----
  const int cpx = (BATCHN * NPOS) / NXCD;          // 2016
  const int raw = blockIdx.x;
  const int blk = (raw % NXCD) * cpx + raw / NXCD; // b*126+i, chunked per XCD

  const int b = blk / NPOS;
  const int i = blk - b * NPOS;
  const int t = threadIdx.x;

  // ---- stage rows 2i..2i+5 into LDS ----
  // row = idx % 6 interleave: consecutive lanes hit different rows so LDS-write
  // bank = (11*row + 4*col4 + e) breaks the stride-4 pattern. Global side:
  // ~21 cache lines/wave-instr vs 16 ideal -- fine for the small read stream.
  const float* src = x + (size_t)b * (IMG * IMG) + (size_t)(2 * i) * IMG;
  for (int idx = t; idx < PSZ * (IMG / 4); idx += 256) {   // 384 float4s
    const int col4 = idx / PSZ;
    const int row  = idx - col4 * PSZ;
    float4 v = reinterpret_cast<const float4*>(src + row * IMG)[col4];
    float* d = &tile[row * LDSW + col4 * 4];
    d[0] = v.x; d[1] = v.y; d[2] = v.z; d[3] = v.w;        // LDSW odd -> scalar writes
  }
  __syncthreads();

  // ---- emit 126 patches: stride-252 so per-thread gather geometry is invariant ----
  // q = t + 252*it  =>  f = 4t + 1008*it; 1008 = 28*36 so j = t/9 + 28*it and
  // k0 = 4*(t mod 9) is constant per thread. LDS addrs just advance by 2*28 = 56.
  if (t < 252) {
    const int tj = t / 9;
    const int m  = t - 9 * tj;
    const int k0 = 4 * m;
    int a0, a1, a2, a3;
    {
      const int k = k0;     const int r = k / PSZ, c = k - PSZ * r; a0 = r * LDSW + 2 * tj + c;
    }
    {
      const int k = k0 + 1; const int r = k / PSZ, c = k - PSZ * r; a1 = r * LDSW + 2 * tj + c;
    }
    {
      const int k = k0 + 2; const int r = k / PSZ, c = k - PSZ * r; a2 = r * LDSW + 2 * tj + c;
    }
    {
      const int k = k0 + 3; const int r = k / PSZ, c = k - PSZ * r; a3 = r * LDSW + 2 * tj + c;
    }
    float4* outp = reinterpret_cast<float4*>(
        out + ((size_t)b * (NPOS * NPOS) + (size_t)i * NPOS) * (PSZ * PSZ));
    int q = t;
#pragma unroll
    for (int it = 0; it < 4; ++it) {                       // 4*252 = 1008 float4s
      float4 v;
      v.x = tile[a0]; v.y = tile[a1]; v.z = tile[a2]; v.w = tile[a3];
      outp[q] = v;
      a0 += 56; a1 += 56; a2 += 56; a3 += 56;
      q += 252;
    }
    if (t < 126) {                                         // tail: q = 1008..1133
      float4 v;
      v.x = tile[a0]; v.y = tile[a1]; v.z = tile[a2]; v.w = tile[a3];
      outp[q] = v;
    }
  }
}

extern "C" void kernel_launch(void* const* d_in, const int* in_sizes, int n_in,
                              void* d_out, int out_size, void* d_ws, size_t ws_size,
                              hipStream_t stream) {
  const float* x = (const float*)d_in[0];
  float* out = (float*)d_out;
  image2patch_kernel<<<BATCHN * NPOS, 256, 0, stream>>>(x, out);
}